// Round 4
// baseline (128.356 us; speedup 1.0000x reference)
//
#include <hip/hip_runtime.h>
#include <hip/hip_bf16.h>
#include <math.h>

// ---------------- problem constants ----------------
#define S        2048
#define HIDDEN   1024
#define NH       16
#define NKV      4
#define HD       64
#define NQKV     1536         // 1024 q + 256 k + 256 v

typedef _Float16 f16x8 __attribute__((ext_vector_type(8)));
typedef _Float16 f16x4 __attribute__((ext_vector_type(4)));
typedef float    f32x4 __attribute__((ext_vector_type(4)));

// ---------------- prep: 4 weight transposes, one launch ----------------
__global__ __launch_bounds__(256) void prep_kernel(const float* __restrict__ wq, const float* __restrict__ wk,
                                                   const float* __restrict__ wvv, const float* __restrict__ wo,
                                                   _Float16* __restrict__ wqkvT, _Float16* __restrict__ woT) {
    int bid = blockIdx.x;
    int tid = threadIdx.x;
    const float* src; _Float16* dst; int Cn, b;
    if (bid < 1024)      { src = wq;  dst = wqkvT;                       Cn = 1024; b = bid; }
    else if (bid < 1280) { src = wk;  dst = wqkvT + (size_t)1024 * 1024; Cn = 256;  b = bid - 1024; }
    else if (bid < 1536) { src = wvv; dst = wqkvT + (size_t)1280 * 1024; Cn = 256;  b = bid - 1280; }
    else                 { src = wo;  dst = woT;                         Cn = 1024; b = bid - 1536; }
    int xb = Cn >> 5;
    int c0 = (b % xb) * 32;
    int r0 = (b / xb) * 32;
    __shared__ float t[32][33];
    int tx = tid & 31, ty = tid >> 5;
#pragma unroll
    for (int i = ty; i < 32; i += 8)
        t[i][tx] = src[(size_t)(r0 + i) * Cn + c0 + tx];
    __syncthreads();
#pragma unroll
    for (int i = ty; i < 32; i += 8)
        dst[(size_t)(c0 + i) * 1024 + r0 + tx] = (_Float16)t[tx][i];
}

// ---------------- pipelined MFMA GEMM: C[M][N] = A[M][K] * BT[N][K]^T ----------------
// 128(M)x64(N) block tile, 4 waves 2x2, wave tile 64x32, BK=64.
// Register-prefetch double-buffer: buffer_load next tile -> compute current from
// LDS -> ds_write prefetched regs (vmcnt wait lands AFTER the MFMAs) -> one
// barrier. Global loads stay in flight across compute (the overlap the
// glds16+barrier structure cannot express). A source templated: f32 (fused
// convert, QKV) or f16 (O proj).
template <bool F32A, typename OutT>
__global__ __launch_bounds__(256) void gemm_pipe(const void* __restrict__ Avoid,
                                                 const _Float16* __restrict__ BT,
                                                 OutT* __restrict__ C,
                                                 int M, int N, int K) {
    const float*    Af = (const float*)Avoid;
    const _Float16* Ah = (const _Float16*)Avoid;
    const int m0   = blockIdx.y * 128;
    const int n0   = blockIdx.x * 64;
    const int tid  = threadIdx.x;
    const int lane = tid & 63;
    const int wv   = tid >> 6;
    const int lr   = lane & 15;
    const int quad = lane >> 4;
    const int wm   = (wv >> 1) * 64;
    const int wn   = (wv & 1) * 32;

    __shared__ __align__(16) _Float16 As[2][128 * 64];   // 2 x 16 KB
    __shared__ __align__(16) _Float16 Bs[2][64 * 64];    // 2 x  8 KB

    // staging maps
    const int ar8 = tid >> 3, ac8 = tid & 7;     // f16 A / B: (row, 16B-chunk)
    const int ar4 = tid >> 4, ac4 = tid & 15;    // f32 A: (row, 16B-f32-chunk=4 floats)

    f32x4 acc[4][2] = {};
    float4 aRf[8];
    uint4  aRh[4];
    uint4  bR[2];

    // ---- prologue: stage tile k0=0 ----
    if (F32A) {
#pragma unroll
        for (int i = 0; i < 8; ++i) {
            int r = ar4 + i * 16;
            float4 v = *(const float4*)(Af + (size_t)(m0 + r) * K + ac4 * 4);
            f16x4 h = { (_Float16)v.x, (_Float16)v.y, (_Float16)v.z, (_Float16)v.w };
            *(f16x4*)&As[0][r * 64 + ac4 * 4] = h;
        }
    } else {
#pragma unroll
        for (int i = 0; i < 4; ++i) {
            int r = ar8 + i * 32;
            *(uint4*)&As[0][r * 64 + ac8 * 8] = *(const uint4*)(Ah + (size_t)(m0 + r) * K + ac8 * 8);
        }
    }
#pragma unroll
    for (int i = 0; i < 2; ++i) {
        int r = ar8 + i * 32;
        *(uint4*)&Bs[0][r * 64 + ac8 * 8] = *(const uint4*)(BT + (size_t)(n0 + r) * K + ac8 * 8);
    }
    __syncthreads();

    int p = 0;
    for (int k0 = 64; k0 < K; k0 += 64) {
        // ---- issue next-tile loads into registers (no use yet) ----
        if (F32A) {
#pragma unroll
            for (int i = 0; i < 8; ++i)
                aRf[i] = *(const float4*)(Af + (size_t)(m0 + ar4 + i * 16) * K + k0 + ac4 * 4);
        } else {
#pragma unroll
            for (int i = 0; i < 4; ++i)
                aRh[i] = *(const uint4*)(Ah + (size_t)(m0 + ar8 + i * 32) * K + k0 + ac8 * 8);
        }
#pragma unroll
        for (int i = 0; i < 2; ++i)
            bR[i] = *(const uint4*)(BT + (size_t)(n0 + ar8 + i * 32) * K + k0 + ac8 * 8);

        // ---- compute current tile ----
#pragma unroll
        for (int ks = 0; ks < 2; ++ks) {
            f16x8 a[4], b[2];
#pragma unroll
            for (int i = 0; i < 4; ++i)
                a[i] = *(const f16x8*)&As[p][(wm + i * 16 + lr) * 64 + (ks * 4 + quad) * 8];
#pragma unroll
            for (int j = 0; j < 2; ++j)
                b[j] = *(const f16x8*)&Bs[p][(wn + j * 16 + lr) * 64 + (ks * 4 + quad) * 8];
#pragma unroll
            for (int i = 0; i < 4; ++i)
#pragma unroll
                for (int j = 0; j < 2; ++j)
                    acc[i][j] = __builtin_amdgcn_mfma_f32_16x16x32_f16(a[i], b[j], acc[i][j], 0, 0, 0);
        }

        // ---- write prefetched regs to the other buffer ----
        if (F32A) {
#pragma unroll
            for (int i = 0; i < 8; ++i) {
                float4 v = aRf[i];
                f16x4 h = { (_Float16)v.x, (_Float16)v.y, (_Float16)v.z, (_Float16)v.w };
                *(f16x4*)&As[p ^ 1][(ar4 + i * 16) * 64 + ac4 * 4] = h;
            }
        } else {
#pragma unroll
            for (int i = 0; i < 4; ++i)
                *(uint4*)&As[p ^ 1][(ar8 + i * 32) * 64 + ac8 * 8] = aRh[i];
        }
#pragma unroll
        for (int i = 0; i < 2; ++i)
            *(uint4*)&Bs[p ^ 1][(ar8 + i * 32) * 64 + ac8 * 8] = bR[i];
        __syncthreads();
        p ^= 1;
    }

    // ---- final tile compute ----
#pragma unroll
    for (int ks = 0; ks < 2; ++ks) {
        f16x8 a[4], b[2];
#pragma unroll
        for (int i = 0; i < 4; ++i)
            a[i] = *(const f16x8*)&As[p][(wm + i * 16 + lr) * 64 + (ks * 4 + quad) * 8];
#pragma unroll
        for (int j = 0; j < 2; ++j)
            b[j] = *(const f16x8*)&Bs[p][(wn + j * 16 + lr) * 64 + (ks * 4 + quad) * 8];
#pragma unroll
        for (int i = 0; i < 4; ++i)
#pragma unroll
            for (int j = 0; j < 2; ++j)
                acc[i][j] = __builtin_amdgcn_mfma_f32_16x16x32_f16(a[i], b[j], acc[i][j], 0, 0, 0);
    }

    // C/D layout: col=lane&15, row=quad*4+reg  [m89/m91]
#pragma unroll
    for (int i = 0; i < 4; ++i)
#pragma unroll
        for (int j = 0; j < 2; ++j)
#pragma unroll
            for (int r = 0; r < 4; ++r)
                C[(size_t)(m0 + wm + i * 16 + quad * 4 + r) * N + n0 + wn + j * 16 + lr] = (OutT)acc[i][j][r];
}

// ---------------- MFMA sliding-window attention with fused RoPE ----------------
__global__ __launch_bounds__(256) void attn_mfma(const _Float16* __restrict__ qkv,
                                                 const int* __restrict__ mask,
                                                 const int* __restrict__ pos_ids,
                                                 _Float16* __restrict__ attn_out) {
    const int s0   = blockIdx.x * 16;
    const int g    = blockIdx.y;
    const int tid  = threadIdx.x;
    const int lane = tid & 63;
    const int wv   = tid >> 6;
    const int h    = g * 4 + wv;
    const int lr   = lane & 15;
    const int quad = lane >> 4;

    __shared__ __align__(16) _Float16 K_lds[80 * 72];
    __shared__ __align__(16) _Float16 Vt_lds[64 * 104];
    __shared__ __align__(16) _Float16 P_lds[4][16 * 104];
    __shared__ int M_lds[1024];
    __shared__ double invf[32];

    ((int4*)M_lds)[tid] = ((const int4*)(mask + s0 * 64))[tid];
    if (tid < 32) invf[tid] = pow(10000.0, -(double)(2 * tid) / 64.0);
    __syncthreads();

    // K staging + rope: 320 units = 80 rows x 4 low-chunks
    for (int c = tid; c < 320; c += 256) {
        int r = c >> 2, cl = c & 3;
        int j = s0 - 63 + r;
        f16x8 nlo = {}, nhi = {};
        if (j >= 0 && r < 79) {
            f16x8 lo = *(const f16x8*)(qkv + (size_t)j * NQKV + 1024 + g * 64 + cl * 8);
            f16x8 hi = *(const f16x8*)(qkv + (size_t)j * NQKV + 1024 + g * 64 + 32 + cl * 8);
            int pos = pos_ids[j];
#pragma unroll
            for (int e = 0; e < 8; ++e) {
                float ang = (float)((double)pos * invf[cl * 8 + e]);
                float sn, cs;
                sincosf(ang, &sn, &cs);
                float x1 = (float)lo[e], x2 = (float)hi[e];
                nlo[e] = (_Float16)(x1 * cs - x2 * sn);
                nhi[e] = (_Float16)(x2 * cs + x1 * sn);
            }
        }
        *(f16x8*)&K_lds[r * 72 + cl * 8]       = nlo;
        *(f16x8*)&K_lds[r * 72 + (cl + 4) * 8] = nhi;
    }
    // V staging transposed: Vt[d][r]
    for (int c = tid; c < 96 * 8; c += 256) {
        int r = c >> 3, cl = c & 7;
        int j = s0 - 63 + r;
        f16x8 val = {};
        if (j >= 0 && r < 79)
            val = *(const f16x8*)(qkv + (size_t)j * NQKV + 1280 + g * 64 + cl * 8);
#pragma unroll
        for (int d8 = 0; d8 < 8; ++d8)
            Vt_lds[(cl * 8 + d8) * 104 + r] = val[d8];
    }

    // Q frags + rope + 1/8 scale
    f16x8 qf[2];
    {
        int posq = pos_ids[s0 + lr];
        f16x8 q0 = *(const f16x8*)(qkv + (size_t)(s0 + lr) * NQKV + h * 64 + quad * 8);
        f16x8 q1 = *(const f16x8*)(qkv + (size_t)(s0 + lr) * NQKV + h * 64 + 32 + quad * 8);
        f16x8 n0, n1;
#pragma unroll
        for (int e = 0; e < 8; ++e) {
            float ang = (float)((double)posq * invf[quad * 8 + e]);
            float sn, cs;
            sincosf(ang, &sn, &cs);
            float x1 = (float)q0[e], x2 = (float)q1[e];
            n0[e] = (_Float16)((x1 * cs - x2 * sn) * 0.125f);
            n1[e] = (_Float16)((x2 * cs + x1 * sn) * 0.125f);
        }
        qf[0] = n0; qf[1] = n1;
    }
    __syncthreads();

    f32x4 sc[5];
#pragma unroll
    for (int t = 0; t < 5; ++t) {
        f32x4 a = {};
#pragma unroll
        for (int ks = 0; ks < 2; ++ks) {
            f16x8 kf = *(const f16x8*)&K_lds[(t * 16 + lr) * 72 + ks * 32 + quad * 8];
            a = __builtin_amdgcn_mfma_f32_16x16x32_f16(qf[ks], kf, a, 0, 0, 0);
        }
        sc[t] = a;
    }

#pragma unroll
    for (int t = 0; t < 5; ++t)
#pragma unroll
        for (int r = 0; r < 4; ++r) {
            int qi = quad * 4 + r;
            int w  = t * 16 + lr - qi;
            bool ok = (w >= 0) && (w < 64) && (M_lds[qi * 64 + (w & 63)] > 0);
            sc[t][r] = ok ? sc[t][r] : -1e30f;
        }

    float pr[5][4];
#pragma unroll
    for (int r = 0; r < 4; ++r) {
        float mx = -1e30f;
#pragma unroll
        for (int t = 0; t < 5; ++t) mx = fmaxf(mx, sc[t][r]);
#pragma unroll
        for (int off = 1; off < 16; off <<= 1) mx = fmaxf(mx, __shfl_xor(mx, off));
        float sum = 0.f;
#pragma unroll
        for (int t = 0; t < 5; ++t) { float e = __expf(sc[t][r] - mx); pr[t][r] = e; sum += e; }
#pragma unroll
        for (int off = 1; off < 16; off <<= 1) sum += __shfl_xor(sum, off);
        float rs = 1.0f / sum;
#pragma unroll
        for (int t = 0; t < 5; ++t) pr[t][r] *= rs;
    }

    _Float16* myP = P_lds[wv];
    {
        f16x4 z = {};
        *(f16x4*)&myP[lr * 104 + 80 + quad * 4] = z;
    }
#pragma unroll
    for (int t = 0; t < 5; ++t)
#pragma unroll
        for (int r = 0; r < 4; ++r)
            myP[(quad * 4 + r) * 104 + t * 16 + lr] = (_Float16)pr[t][r];
    __syncthreads();

    f32x4 oacc[4] = {};
#pragma unroll
    for (int ks = 0; ks < 3; ++ks) {
        f16x8 pf = *(const f16x8*)&myP[lr * 104 + ks * 32 + quad * 8];
#pragma unroll
        for (int t = 0; t < 4; ++t) {
            f16x8 vf = *(const f16x8*)&Vt_lds[(t * 16 + lr) * 104 + ks * 32 + quad * 8];
            oacc[t] = __builtin_amdgcn_mfma_f32_16x16x32_f16(pf, vf, oacc[t], 0, 0, 0);
        }
    }
#pragma unroll
    for (int t = 0; t < 4; ++t)
#pragma unroll
        for (int r = 0; r < 4; ++r)
            attn_out[(size_t)(s0 + quad * 4 + r) * HIDDEN + h * 64 + t * 16 + lr] = (_Float16)oacc[t][r];
}

// ---------------- launch ----------------
extern "C" void kernel_launch(void* const* d_in, const int* in_sizes, int n_in,
                              void* d_out, int out_size, void* d_ws, size_t ws_size,
                              hipStream_t stream) {
    const float* hs      = (const float*)d_in[0];
    const int*   mask    = (const int*)  d_in[1];
    const int*   pos_ids = (const int*)  d_in[2];
    const float* wq      = (const float*)d_in[3];
    const float* wk      = (const float*)d_in[4];
    const float* wvv     = (const float*)d_in[5];
    const float* wo      = (const float*)d_in[6];
    float* out = (float*)d_out;

    char* ws = (char*)d_ws;
    _Float16* wqkvT   = (_Float16*)(ws + 0);                    // 1536x1024   (3 MB)
    _Float16* woT     = (_Float16*)(ws + (3u << 20));           // 1024x1024   (2 MB)
    _Float16* qkvf16  = (_Float16*)(ws + (5u << 20));           // 2048x1536   (6 MB)
    _Float16* attnf16 = (_Float16*)(ws + (11u << 20));          // 2048x1024   (4 MB)

    // 1. weight transposes
    prep_kernel<<<2560, 256, 0, stream>>>(wq, wk, wvv, wo, wqkvT, woT);
    // 2. QKV projection (A = hs f32, converted in-staging) -> qkvf16
    gemm_pipe<true, _Float16><<<dim3(NQKV / 64, S / 128), 256, 0, stream>>>(hs, wqkvT, qkvf16, S, NQKV, HIDDEN);
    // 3. attention (rope fused) -> attnf16
    attn_mfma<<<dim3(S / 16, NKV), 256, 0, stream>>>(qkvf16, mask, pos_ids, attnf16);
    // 4. output projection -> d_out f32
    gemm_pipe<false, float><<<dim3(HIDDEN / 64, S / 128), 256, 0, stream>>>(attnf16, woT, out, S, HIDDEN, HIDDEN);
}

// Round 5
// 119.035 us; speedup vs baseline: 1.0783x; 1.0783x over previous
//
#include <hip/hip_runtime.h>
#include <hip/hip_bf16.h>
#include <math.h>

// ---------------- problem constants ----------------
#define S        2048
#define HIDDEN   1024
#define NH       16
#define NKV      4
#define HD       64
#define NQKV     1536         // 1024 q + 256 k + 256 v
#define VW       2128         // vTs row width: 64 halo + 2048 + 16 tail

typedef _Float16 f16x8 __attribute__((ext_vector_type(8)));
typedef _Float16 f16x4 __attribute__((ext_vector_type(4)));
typedef float    f32x4 __attribute__((ext_vector_type(4)));

// ---------------- prep: weight transposes + hs convert + rope table + v halo ----------------
__global__ __launch_bounds__(256) void prep_kernel(const float* __restrict__ hs, _Float16* __restrict__ hsf16,
                                                   const float* __restrict__ wq, const float* __restrict__ wk,
                                                   const float* __restrict__ wvv, const float* __restrict__ wo,
                                                   _Float16* __restrict__ wqkvT, _Float16* __restrict__ woT,
                                                   const int* __restrict__ pos_ids, float2* __restrict__ rope_tab,
                                                   _Float16* __restrict__ vTs) {
    int bid = blockIdx.x;
    int tid = threadIdx.x;
    if (bid >= 4864) {                       // v-halo zero region: 256 blocks (one per d row)
        int d = bid - 4864;
        if (tid < 64) vTs[(size_t)d * VW + tid] = (_Float16)0.0f;
        return;
    }
    if (bid >= 4608) {                       // rope table region: 256 blocks, 2048x32 entries
        int idx = (bid - 4608) * 256 + tid;
        int s = idx >> 5, f = idx & 31;
        double inv = pow(10000.0, -(double)(2 * f) / 64.0);
        float ang = (float)((double)pos_ids[s] * inv);
        float sn, cs;
        sincosf(ang, &sn, &cs);
        rope_tab[idx] = make_float2(sn, cs);
        return;
    }
    if (bid >= 2560) {                       // hs f32->f16 convert: 2048 blocks
        int i = (bid - 2560) * 256 + tid;
        float4 v = ((const float4*)hs)[i];
        f16x4 o = { (_Float16)v.x, (_Float16)v.y, (_Float16)v.z, (_Float16)v.w };
        *(f16x4*)(hsf16 + 4 * (size_t)i) = o;
        return;
    }
    // weight transpose region: src [1024][Cn] f32 -> dst [Cn][1024] f16
    const float* src; _Float16* dst; int Cn, b;
    if (bid < 1024)      { src = wq;  dst = wqkvT;                       Cn = 1024; b = bid; }
    else if (bid < 1280) { src = wk;  dst = wqkvT + (size_t)1024 * 1024; Cn = 256;  b = bid - 1024; }
    else if (bid < 1536) { src = wvv; dst = wqkvT + (size_t)1280 * 1024; Cn = 256;  b = bid - 1280; }
    else                 { src = wo;  dst = woT;                         Cn = 1024; b = bid - 1536; }
    int xb = Cn >> 5;
    int c0 = (b % xb) * 32;
    int r0 = (b / xb) * 32;
    __shared__ float t[32][33];
    int tx = tid & 31, ty = tid >> 5;
#pragma unroll
    for (int i = ty; i < 32; i += 8)
        t[i][tx] = src[(size_t)(r0 + i) * Cn + c0 + tx];
    __syncthreads();
#pragma unroll
    for (int i = ty; i < 32; i += 8)
        dst[(size_t)(c0 + i) * 1024 + r0 + tx] = (_Float16)t[tx][i];
}

// ---------------- QKV GEMM with fused rope / v-transpose epilogue ----------------
// 128(M)x64(N) block tile, 4 waves stacked in M (wave tile 32x64, acc[2][4]).
// Register-prefetch double-buffer; LDS stride 72 f16 (144B = 9x16: aligned, 2-way-only banks).
// Epilogue: q cols -> rope + 0.125 scale; k cols -> rope; v cols -> transposed store to vTs.
__global__ __launch_bounds__(256) void gemm_qkv(const _Float16* __restrict__ A,
                                                const _Float16* __restrict__ BT,
                                                _Float16* __restrict__ qkv,
                                                _Float16* __restrict__ vTs,
                                                const float2* __restrict__ rope_tab) {
    const int K = HIDDEN;
    const int m0   = blockIdx.y * 128;
    const int n0   = blockIdx.x * 64;
    const int tid  = threadIdx.x;
    const int lane = tid & 63;
    const int wv   = tid >> 6;
    const int lr   = lane & 15;
    const int quad = lane >> 4;
    const int wm   = wv * 32;

    __shared__ __align__(16) _Float16 As[2][128 * 72];
    __shared__ __align__(16) _Float16 Bs[2][64 * 72];

    const int ar8 = tid >> 3, ac8 = tid & 7;

    f32x4 acc[2][4] = {};
    uint4 aR[4], bR[2];

    // prologue: stage k0=0
#pragma unroll
    for (int i = 0; i < 4; ++i)
        *(uint4*)&As[0][(ar8 + i * 32) * 72 + ac8 * 8] = *(const uint4*)(A + (size_t)(m0 + ar8 + i * 32) * K + ac8 * 8);
#pragma unroll
    for (int i = 0; i < 2; ++i)
        *(uint4*)&Bs[0][(ar8 + i * 32) * 72 + ac8 * 8] = *(const uint4*)(BT + (size_t)(n0 + ar8 + i * 32) * K + ac8 * 8);
    __syncthreads();

    int p = 0;
    for (int k0 = 64; k0 < K; k0 += 64) {
#pragma unroll
        for (int i = 0; i < 4; ++i)
            aR[i] = *(const uint4*)(A + (size_t)(m0 + ar8 + i * 32) * K + k0 + ac8 * 8);
#pragma unroll
        for (int i = 0; i < 2; ++i)
            bR[i] = *(const uint4*)(BT + (size_t)(n0 + ar8 + i * 32) * K + k0 + ac8 * 8);
#pragma unroll
        for (int ks = 0; ks < 2; ++ks) {
            f16x8 a[2], b[4];
#pragma unroll
            for (int i = 0; i < 2; ++i)
                a[i] = *(const f16x8*)&As[p][(wm + i * 16 + lr) * 72 + (ks * 4 + quad) * 8];
#pragma unroll
            for (int j = 0; j < 4; ++j)
                b[j] = *(const f16x8*)&Bs[p][(j * 16 + lr) * 72 + (ks * 4 + quad) * 8];
#pragma unroll
            for (int i = 0; i < 2; ++i)
#pragma unroll
                for (int j = 0; j < 4; ++j)
                    acc[i][j] = __builtin_amdgcn_mfma_f32_16x16x32_f16(a[i], b[j], acc[i][j], 0, 0, 0);
        }
#pragma unroll
        for (int i = 0; i < 4; ++i)
            *(uint4*)&As[p ^ 1][(ar8 + i * 32) * 72 + ac8 * 8] = aR[i];
#pragma unroll
        for (int i = 0; i < 2; ++i)
            *(uint4*)&Bs[p ^ 1][(ar8 + i * 32) * 72 + ac8 * 8] = bR[i];
        __syncthreads();
        p ^= 1;
    }
#pragma unroll
    for (int ks = 0; ks < 2; ++ks) {
        f16x8 a[2], b[4];
#pragma unroll
        for (int i = 0; i < 2; ++i)
            a[i] = *(const f16x8*)&As[p][(wm + i * 16 + lr) * 72 + (ks * 4 + quad) * 8];
#pragma unroll
        for (int j = 0; j < 4; ++j)
            b[j] = *(const f16x8*)&Bs[p][(j * 16 + lr) * 72 + (ks * 4 + quad) * 8];
#pragma unroll
        for (int i = 0; i < 2; ++i)
#pragma unroll
            for (int j = 0; j < 4; ++j)
                acc[i][j] = __builtin_amdgcn_mfma_f32_16x16x32_f16(a[i], b[j], acc[i][j], 0, 0, 0);
    }

    // epilogue. C/D layout: col=lane&15 (+j*16), row=quad*4+reg  [m89/m91]
    if (n0 < 1280) {
        const bool isq = (n0 < 1024);
#pragma unroll
        for (int i = 0; i < 2; ++i)
#pragma unroll
            for (int r = 0; r < 4; ++r) {
                int s = m0 + wm + i * 16 + quad * 4 + r;
                const float2* tb = rope_tab + (size_t)s * 32;
#pragma unroll
                for (int j = 0; j < 2; ++j) {
                    float2 sc = tb[j * 16 + lr];
                    float lo = acc[i][j][r], hi = acc[i][j + 2][r];
                    float nlo = lo * sc.y - hi * sc.x;
                    float nhi = hi * sc.y + lo * sc.x;
                    if (isq) { nlo *= 0.125f; nhi *= 0.125f; }
                    qkv[(size_t)s * NQKV + n0 + j * 16 + lr]      = (_Float16)nlo;
                    qkv[(size_t)s * NQKV + n0 + 32 + j * 16 + lr] = (_Float16)nhi;
                }
            }
    } else {
#pragma unroll
        for (int i = 0; i < 2; ++i)
#pragma unroll
            for (int j = 0; j < 4; ++j) {
                int d = n0 - 1280 + j * 16 + lr;
                f16x4 h = { (_Float16)acc[i][j][0], (_Float16)acc[i][j][1],
                            (_Float16)acc[i][j][2], (_Float16)acc[i][j][3] };
                *(f16x4*)(vTs + (size_t)d * VW + 64 + m0 + wm + i * 16 + quad * 4) = h;
            }
    }
}

// ---------------- O-proj GEMM (f16 A, f32 out), same pipeline, 2x2 wave grid ----------------
__global__ __launch_bounds__(256) void gemm_o(const _Float16* __restrict__ A,
                                              const _Float16* __restrict__ BT,
                                              float* __restrict__ C) {
    const int K = HIDDEN, N = HIDDEN;
    const int m0   = blockIdx.y * 128;
    const int n0   = blockIdx.x * 64;
    const int tid  = threadIdx.x;
    const int lane = tid & 63;
    const int wv   = tid >> 6;
    const int lr   = lane & 15;
    const int quad = lane >> 4;
    const int wm   = (wv >> 1) * 64;
    const int wn   = (wv & 1) * 32;

    __shared__ __align__(16) _Float16 As[2][128 * 72];
    __shared__ __align__(16) _Float16 Bs[2][64 * 72];

    const int ar8 = tid >> 3, ac8 = tid & 7;
    f32x4 acc[4][2] = {};
    uint4 aR[4], bR[2];

#pragma unroll
    for (int i = 0; i < 4; ++i)
        *(uint4*)&As[0][(ar8 + i * 32) * 72 + ac8 * 8] = *(const uint4*)(A + (size_t)(m0 + ar8 + i * 32) * K + ac8 * 8);
#pragma unroll
    for (int i = 0; i < 2; ++i)
        *(uint4*)&Bs[0][(ar8 + i * 32) * 72 + ac8 * 8] = *(const uint4*)(BT + (size_t)(n0 + ar8 + i * 32) * K + ac8 * 8);
    __syncthreads();

    int p = 0;
    for (int k0 = 64; k0 < K; k0 += 64) {
#pragma unroll
        for (int i = 0; i < 4; ++i)
            aR[i] = *(const uint4*)(A + (size_t)(m0 + ar8 + i * 32) * K + k0 + ac8 * 8);
#pragma unroll
        for (int i = 0; i < 2; ++i)
            bR[i] = *(const uint4*)(BT + (size_t)(n0 + ar8 + i * 32) * K + k0 + ac8 * 8);
#pragma unroll
        for (int ks = 0; ks < 2; ++ks) {
            f16x8 a[4], b[2];
#pragma unroll
            for (int i = 0; i < 4; ++i)
                a[i] = *(const f16x8*)&As[p][(wm + i * 16 + lr) * 72 + (ks * 4 + quad) * 8];
#pragma unroll
            for (int j = 0; j < 2; ++j)
                b[j] = *(const f16x8*)&Bs[p][(wn + j * 16 + lr) * 72 + (ks * 4 + quad) * 8];
#pragma unroll
            for (int i = 0; i < 4; ++i)
#pragma unroll
                for (int j = 0; j < 2; ++j)
                    acc[i][j] = __builtin_amdgcn_mfma_f32_16x16x32_f16(a[i], b[j], acc[i][j], 0, 0, 0);
        }
#pragma unroll
        for (int i = 0; i < 4; ++i)
            *(uint4*)&As[p ^ 1][(ar8 + i * 32) * 72 + ac8 * 8] = aR[i];
#pragma unroll
        for (int i = 0; i < 2; ++i)
            *(uint4*)&Bs[p ^ 1][(ar8 + i * 32) * 72 + ac8 * 8] = bR[i];
        __syncthreads();
        p ^= 1;
    }
#pragma unroll
    for (int ks = 0; ks < 2; ++ks) {
        f16x8 a[4], b[2];
#pragma unroll
        for (int i = 0; i < 4; ++i)
            a[i] = *(const f16x8*)&As[p][(wm + i * 16 + lr) * 72 + (ks * 4 + quad) * 8];
#pragma unroll
        for (int j = 0; j < 2; ++j)
            b[j] = *(const f16x8*)&Bs[p][(wn + j * 16 + lr) * 72 + (ks * 4 + quad) * 8];
#pragma unroll
        for (int i = 0; i < 4; ++i)
#pragma unroll
            for (int j = 0; j < 2; ++j)
                acc[i][j] = __builtin_amdgcn_mfma_f32_16x16x32_f16(a[i], b[j], acc[i][j], 0, 0, 0);
    }
#pragma unroll
    for (int i = 0; i < 4; ++i)
#pragma unroll
        for (int j = 0; j < 2; ++j)
#pragma unroll
            for (int r = 0; r < 4; ++r)
                C[(size_t)(m0 + wm + i * 16 + quad * 4 + r) * N + n0 + wn + j * 16 + lr] = acc[i][j][r];
}

// ---------------- MFMA sliding-window attention (rope pre-applied) ----------------
// Band base s0-64: row r in [0,96) <-> key j = s0-64+r. Window for query qi:
// r in [qi+1, qi+64]. r=0 and r>=80 always masked / zero-P. All LDS/global
// vector accesses 16B-aligned by construction.
__global__ __launch_bounds__(256) void attn_mfma(const _Float16* __restrict__ qkv,
                                                 const _Float16* __restrict__ vTs,
                                                 const int* __restrict__ mask,
                                                 _Float16* __restrict__ attn_out) {
    const int s0   = blockIdx.x * 16;
    const int g    = blockIdx.y;
    const int tid  = threadIdx.x;
    const int lane = tid & 63;
    const int wv   = tid >> 6;
    const int h    = g * 4 + wv;
    const int lr   = lane & 15;
    const int quad = lane >> 4;

    __shared__ __align__(16) _Float16 K_lds[80 * 72];
    __shared__ __align__(16) _Float16 Vt_lds[64 * 104];
    __shared__ __align__(16) _Float16 P_lds[4][16 * 104];
    __shared__ int M_lds[1024];

    ((int4*)M_lds)[tid] = ((const int4*)(mask + s0 * 64))[tid];

    // K band: rows 0..79, key j = s0-64+r (zero j<0; r=0 is masked later anyway)
    for (int c = tid; c < 640; c += 256) {
        int r = c >> 3, cc = c & 7;
        int j = s0 - 64 + r;
        f16x8 val = {};
        if (j >= 0)
            val = *(const f16x8*)(qkv + (size_t)j * NQKV + 1024 + g * 64 + cc * 8);
        *(f16x8*)&K_lds[r * 72 + cc * 8] = val;
    }
    // V band from pre-transposed vTs: Vt_lds[d][r] = vTs[g*64+d][s0 + r], r 0..95.
    // Front halo of vTs is zero; tail reads are finite garbage multiplied by P=0.
    for (int c = tid; c < 64 * 12; c += 256) {
        int d = c / 12, ch = c % 12;
        *(f16x8*)&Vt_lds[d * 104 + ch * 8] =
            *(const f16x8*)(vTs + (size_t)(g * 64 + d) * VW + s0 + ch * 8);
    }

    // Q frags (already roped + 0.125-scaled)
    f16x8 qf[2];
#pragma unroll
    for (int ks = 0; ks < 2; ++ks)
        qf[ks] = *(const f16x8*)(qkv + (size_t)(s0 + lr) * NQKV + h * 64 + ks * 32 + quad * 8);
    __syncthreads();

    // QK^T: 5 key tiles x 2 k-steps
    f32x4 sc[5];
#pragma unroll
    for (int t = 0; t < 5; ++t) {
        f32x4 a = {};
#pragma unroll
        for (int ks = 0; ks < 2; ++ks) {
            f16x8 kf = *(const f16x8*)&K_lds[(t * 16 + lr) * 72 + ks * 32 + quad * 8];
            a = __builtin_amdgcn_mfma_f32_16x16x32_f16(qf[ks], kf, a, 0, 0, 0);
        }
        sc[t] = a;
    }

    // window + attention_mask: w = r - 1 - qi must be in [0,64)
#pragma unroll
    for (int t = 0; t < 5; ++t)
#pragma unroll
        for (int r = 0; r < 4; ++r) {
            int qi = quad * 4 + r;
            int w  = t * 16 + lr - 1 - qi;
            bool ok = (w >= 0) && (w < 64) && (M_lds[qi * 64 + (w & 63)] > 0);
            sc[t][r] = ok ? sc[t][r] : -1e30f;
        }

    // softmax across the 16 lanes of each quad-row
    float pr[5][4];
#pragma unroll
    for (int r = 0; r < 4; ++r) {
        float mx = -1e30f;
#pragma unroll
        for (int t = 0; t < 5; ++t) mx = fmaxf(mx, sc[t][r]);
#pragma unroll
        for (int off = 1; off < 16; off <<= 1) mx = fmaxf(mx, __shfl_xor(mx, off));
        float sum = 0.f;
#pragma unroll
        for (int t = 0; t < 5; ++t) { float e = __expf(sc[t][r] - mx); pr[t][r] = e; sum += e; }
#pragma unroll
        for (int off = 1; off < 16; off <<= 1) sum += __shfl_xor(sum, off);
        float rs = 1.0f / sum;
#pragma unroll
        for (int t = 0; t < 5; ++t) pr[t][r] *= rs;
    }

    // P -> LDS in A-frag layout; zero pad cols 80..95
    _Float16* myP = P_lds[wv];
    {
        f16x4 z = {};
        *(f16x4*)&myP[lr * 104 + 80 + quad * 4] = z;
    }
#pragma unroll
    for (int t = 0; t < 5; ++t)
#pragma unroll
        for (int r = 0; r < 4; ++r)
            myP[(quad * 4 + r) * 104 + t * 16 + lr] = (_Float16)pr[t][r];
    __syncthreads();

    // PV
    f32x4 oacc[4] = {};
#pragma unroll
    for (int ks = 0; ks < 3; ++ks) {
        f16x8 pf = *(const f16x8*)&myP[lr * 104 + ks * 32 + quad * 8];
#pragma unroll
        for (int t = 0; t < 4; ++t) {
            f16x8 vf = *(const f16x8*)&Vt_lds[(t * 16 + lr) * 104 + ks * 32 + quad * 8];
            oacc[t] = __builtin_amdgcn_mfma_f32_16x16x32_f16(pf, vf, oacc[t], 0, 0, 0);
        }
    }
#pragma unroll
    for (int t = 0; t < 4; ++t)
#pragma unroll
        for (int r = 0; r < 4; ++r)
            attn_out[(size_t)(s0 + quad * 4 + r) * HIDDEN + h * 64 + t * 16 + lr] = (_Float16)oacc[t][r];
}

// ---------------- launch ----------------
extern "C" void kernel_launch(void* const* d_in, const int* in_sizes, int n_in,
                              void* d_out, int out_size, void* d_ws, size_t ws_size,
                              hipStream_t stream) {
    const float* hs      = (const float*)d_in[0];
    const int*   mask    = (const int*)  d_in[1];
    const int*   pos_ids = (const int*)  d_in[2];
    const float* wq      = (const float*)d_in[3];
    const float* wk      = (const float*)d_in[4];
    const float* wvv     = (const float*)d_in[5];
    const float* wo      = (const float*)d_in[6];
    float* out = (float*)d_out;

    char* ws = (char*)d_ws;
    _Float16* wqkvT   = (_Float16*)(ws + 0);                    // 1536x1024 f16 (3 MB)
    _Float16* woT     = (_Float16*)(ws + (3u << 20));           // 1024x1024 f16 (2 MB)
    _Float16* hsf16   = (_Float16*)(ws + (5u << 20));           // 2048x1024 f16 (4 MB)
    _Float16* qkvf16  = (_Float16*)(ws + (9u << 20));           // 2048x1536 f16 (6 MB)
    _Float16* attnf16 = (_Float16*)(ws + (15u << 20));          // 2048x1024 f16 (4 MB)
    _Float16* vTs     = (_Float16*)(ws + (19u << 20));          // 256x2128  f16 (~1.1 MB)
    float2*   ropeTab = (float2*)  (ws + (21u << 20));          // 2048x32 float2 (512 KB)

    // 1. prep: transposes (2560) + convert (2048) + rope table (256) + v halo (256)
    prep_kernel<<<5120, 256, 0, stream>>>(hs, hsf16, wq, wk, wvv, wo, wqkvT, woT,
                                          pos_ids, ropeTab, vTs);
    // 2. QKV projection with fused rope / v-transpose
    gemm_qkv<<<dim3(NQKV / 64, S / 128), 256, 0, stream>>>(hsf16, wqkvT, qkvf16, vTs, ropeTab);
    // 3. attention
    attn_mfma<<<dim3(S / 16, NKV), 256, 0, stream>>>(qkvf16, vTs, mask, attnf16);
    // 4. output projection -> f32 out
    gemm_o<<<dim3(HIDDEN / 64, S / 128), 256, 0, stream>>>(attnf16, woT, out);
}

// Round 6
// 116.257 us; speedup vs baseline: 1.1041x; 1.0239x over previous
//
#include <hip/hip_runtime.h>
#include <hip/hip_bf16.h>
#include <math.h>

// ---------------- problem constants ----------------
#define S        2048
#define HIDDEN   1024
#define NH       16
#define NKV      4
#define HD       64
#define NQKV     1536         // 1024 q + 256 k + 256 v
#define VW       2128         // vTs row width: 64 halo + 2048 + 16 tail

typedef _Float16 f16x8 __attribute__((ext_vector_type(8)));
typedef _Float16 f16x4 __attribute__((ext_vector_type(4)));
typedef float    f32x4 __attribute__((ext_vector_type(4)));

// async 16B global->LDS (DMA, no VGPR round trip). LDS dest = wave-uniform
// base + lane*16 — layout must be lane-linear (no padding).
__device__ __forceinline__ void glds16(const void* g, void* l) {
    __builtin_amdgcn_global_load_lds((const __attribute__((address_space(1))) void*)g,
                                     (__attribute__((address_space(3))) void*)l, 16, 0, 0);
}

// ---------------- prep: weight transposes + hs convert + rope table + v halo ----------------
__global__ __launch_bounds__(256) void prep_kernel(const float* __restrict__ hs, _Float16* __restrict__ hsf16,
                                                   const float* __restrict__ wq, const float* __restrict__ wk,
                                                   const float* __restrict__ wvv, const float* __restrict__ wo,
                                                   _Float16* __restrict__ wqkvT, _Float16* __restrict__ woT,
                                                   const int* __restrict__ pos_ids, float2* __restrict__ rope_tab,
                                                   _Float16* __restrict__ vTs) {
    int bid = blockIdx.x;
    int tid = threadIdx.x;
    if (bid >= 4864) {                       // v-halo zero region: 256 blocks (one per d row)
        int d = bid - 4864;
        if (tid < 64) vTs[(size_t)d * VW + tid] = (_Float16)0.0f;
        return;
    }
    if (bid >= 4608) {                       // rope table region: 256 blocks, 2048x32 entries
        int idx = (bid - 4608) * 256 + tid;
        int s = idx >> 5, f = idx & 31;
        double inv = pow(10000.0, -(double)(2 * f) / 64.0);
        float ang = (float)((double)pos_ids[s] * inv);
        float sn, cs;
        sincosf(ang, &sn, &cs);
        rope_tab[idx] = make_float2(sn, cs);
        return;
    }
    if (bid >= 2560) {                       // hs f32->f16 convert: 2048 blocks
        int i = (bid - 2560) * 256 + tid;
        float4 v = ((const float4*)hs)[i];
        f16x4 o = { (_Float16)v.x, (_Float16)v.y, (_Float16)v.z, (_Float16)v.w };
        *(f16x4*)(hsf16 + 4 * (size_t)i) = o;
        return;
    }
    // weight transpose region: src [1024][Cn] f32 -> dst [Cn][1024] f16
    const float* src; _Float16* dst; int Cn, b;
    if (bid < 1024)      { src = wq;  dst = wqkvT;                       Cn = 1024; b = bid; }
    else if (bid < 1280) { src = wk;  dst = wqkvT + (size_t)1024 * 1024; Cn = 256;  b = bid - 1024; }
    else if (bid < 1536) { src = wvv; dst = wqkvT + (size_t)1280 * 1024; Cn = 256;  b = bid - 1280; }
    else                 { src = wo;  dst = woT;                         Cn = 1024; b = bid - 1536; }
    int xb = Cn >> 5;
    int c0 = (b % xb) * 32;
    int r0 = (b / xb) * 32;
    __shared__ float t[32][33];
    int tx = tid & 31, ty = tid >> 5;
#pragma unroll
    for (int i = ty; i < 32; i += 8)
        t[i][tx] = src[(size_t)(r0 + i) * Cn + c0 + tx];
    __syncthreads();
#pragma unroll
    for (int i = ty; i < 32; i += 8)
        dst[(size_t)(c0 + i) * 1024 + r0 + tx] = (_Float16)t[tx][i];
}

// ---------------- QKV GEMM (m97-style glds16, single-buffer) + fused rope/v-T epilogue ----
// 128(M)x64(N) block tile, 4 waves stacked in M (wave tile 32x64, acc[2][4]).
// LDS 24 KB -> ~6 blocks/CU resident (all 384 blocks co-resident). XOR chunk
// swizzle keeps frag reads conflict-free on the unpadded lane-linear layout:
// LDS[r][cc] holds global chunk cc^(r&7).
__global__ __launch_bounds__(256) void gemm_qkv(const _Float16* __restrict__ A,
                                                const _Float16* __restrict__ BT,
                                                _Float16* __restrict__ qkv,
                                                _Float16* __restrict__ vTs,
                                                const float2* __restrict__ rope_tab) {
    const int K = HIDDEN;
    const int m0   = blockIdx.y * 128;
    const int n0   = blockIdx.x * 64;
    const int tid  = threadIdx.x;
    const int lane = tid & 63;
    const int wv   = tid >> 6;
    const int lr   = lane & 15;
    const int quad = lane >> 4;
    const int wm   = wv * 32;
    const int dr   = lane >> 3;   // staging row-within-octet
    const int cc   = lane & 7;    // staging 16B-chunk

    __shared__ __align__(16) _Float16 As[128 * 64];   // 16 KB
    __shared__ __align__(16) _Float16 Bs[64 * 64];    //  8 KB

    f32x4 acc[2][4] = {};

    for (int k0 = 0; k0 < K; k0 += 64) {
        __syncthreads();
        // A: wave wv stages rows [wv*32, wv*32+32)
#pragma unroll
        for (int t = 0; t < 4; ++t) {
            int r = wv * 32 + t * 8 + dr;
            glds16(A + (size_t)(m0 + r) * K + k0 + (cc ^ (r & 7)) * 8,
                   As + (wv * 32 + t * 8) * 64);
        }
        // B: wave wv stages rows [wv*16, wv*16+16)
#pragma unroll
        for (int t = 0; t < 2; ++t) {
            int r = wv * 16 + t * 8 + dr;
            glds16(BT + (size_t)(n0 + r) * K + k0 + (cc ^ (r & 7)) * 8,
                   Bs + (wv * 16 + t * 8) * 64);
        }
        __syncthreads();
#pragma unroll
        for (int ks = 0; ks < 2; ++ks) {
            f16x8 a[2], b[4];
#pragma unroll
            for (int i = 0; i < 2; ++i) {
                int row = wm + i * 16 + lr;
                a[i] = *(const f16x8*)&As[row * 64 + ((ks * 4 + quad) ^ (row & 7)) * 8];
            }
#pragma unroll
            for (int j = 0; j < 4; ++j) {
                int row = j * 16 + lr;
                b[j] = *(const f16x8*)&Bs[row * 64 + ((ks * 4 + quad) ^ (row & 7)) * 8];
            }
#pragma unroll
            for (int i = 0; i < 2; ++i)
#pragma unroll
                for (int j = 0; j < 4; ++j)
                    acc[i][j] = __builtin_amdgcn_mfma_f32_16x16x32_f16(a[i], b[j], acc[i][j], 0, 0, 0);
        }
    }

    // epilogue. C/D layout: col=lane&15 (+j*16), row=quad*4+reg  [m89/m91]
    if (n0 < 1280) {
        const bool isq = (n0 < 1024);
#pragma unroll
        for (int i = 0; i < 2; ++i)
#pragma unroll
            for (int r = 0; r < 4; ++r) {
                int s = m0 + wm + i * 16 + quad * 4 + r;
                const float2* tb = rope_tab + (size_t)s * 32;
#pragma unroll
                for (int j = 0; j < 2; ++j) {
                    float2 sc = tb[j * 16 + lr];
                    float lo = acc[i][j][r], hi = acc[i][j + 2][r];
                    float nlo = lo * sc.y - hi * sc.x;
                    float nhi = hi * sc.y + lo * sc.x;
                    if (isq) { nlo *= 0.125f; nhi *= 0.125f; }
                    qkv[(size_t)s * NQKV + n0 + j * 16 + lr]      = (_Float16)nlo;
                    qkv[(size_t)s * NQKV + n0 + 32 + j * 16 + lr] = (_Float16)nhi;
                }
            }
    } else {
#pragma unroll
        for (int i = 0; i < 2; ++i)
#pragma unroll
            for (int j = 0; j < 4; ++j) {
                int d = n0 - 1280 + j * 16 + lr;
                f16x4 h = { (_Float16)acc[i][j][0], (_Float16)acc[i][j][1],
                            (_Float16)acc[i][j][2], (_Float16)acc[i][j][3] };
                *(f16x4*)(vTs + (size_t)d * VW + 64 + m0 + wm + i * 16 + quad * 4) = h;
            }
    }
}

// ---------------- O-proj GEMM (same glds16 structure, 2x2 wave grid, f32 out) ----------------
__global__ __launch_bounds__(256) void gemm_o(const _Float16* __restrict__ A,
                                              const _Float16* __restrict__ BT,
                                              float* __restrict__ C) {
    const int K = HIDDEN, N = HIDDEN;
    const int m0   = blockIdx.y * 128;
    const int n0   = blockIdx.x * 64;
    const int tid  = threadIdx.x;
    const int lane = tid & 63;
    const int wv   = tid >> 6;
    const int lr   = lane & 15;
    const int quad = lane >> 4;
    const int wm   = (wv >> 1) * 64;
    const int wn   = (wv & 1) * 32;
    const int dr   = lane >> 3;
    const int cc   = lane & 7;

    __shared__ __align__(16) _Float16 As[128 * 64];
    __shared__ __align__(16) _Float16 Bs[64 * 64];

    f32x4 acc[4][2] = {};

    for (int k0 = 0; k0 < K; k0 += 64) {
        __syncthreads();
#pragma unroll
        for (int t = 0; t < 4; ++t) {
            int r = wv * 32 + t * 8 + dr;
            glds16(A + (size_t)(m0 + r) * K + k0 + (cc ^ (r & 7)) * 8,
                   As + (wv * 32 + t * 8) * 64);
        }
#pragma unroll
        for (int t = 0; t < 2; ++t) {
            int r = wv * 16 + t * 8 + dr;
            glds16(BT + (size_t)(n0 + r) * K + k0 + (cc ^ (r & 7)) * 8,
                   Bs + (wv * 16 + t * 8) * 64);
        }
        __syncthreads();
#pragma unroll
        for (int ks = 0; ks < 2; ++ks) {
            f16x8 a[4], b[2];
#pragma unroll
            for (int i = 0; i < 4; ++i) {
                int row = wm + i * 16 + lr;
                a[i] = *(const f16x8*)&As[row * 64 + ((ks * 4 + quad) ^ (row & 7)) * 8];
            }
#pragma unroll
            for (int j = 0; j < 2; ++j) {
                int row = wn + j * 16 + lr;
                b[j] = *(const f16x8*)&Bs[row * 64 + ((ks * 4 + quad) ^ (row & 7)) * 8];
            }
#pragma unroll
            for (int i = 0; i < 4; ++i)
#pragma unroll
                for (int j = 0; j < 2; ++j)
                    acc[i][j] = __builtin_amdgcn_mfma_f32_16x16x32_f16(a[i], b[j], acc[i][j], 0, 0, 0);
        }
    }
#pragma unroll
    for (int i = 0; i < 4; ++i)
#pragma unroll
        for (int j = 0; j < 2; ++j)
#pragma unroll
            for (int r = 0; r < 4; ++r)
                C[(size_t)(m0 + wm + i * 16 + quad * 4 + r) * N + n0 + wn + j * 16 + lr] = acc[i][j][r];
}

// ---------------- MFMA sliding-window attention (rope pre-applied) ----------------
// Band base s0-64: row r in [0,96) <-> key j = s0-64+r. Window for query qi:
// r in [qi+1, qi+64]. r=0 and r>=80 always masked / zero-P. All LDS/global
// vector accesses 16B-aligned by construction.
__global__ __launch_bounds__(256) void attn_mfma(const _Float16* __restrict__ qkv,
                                                 const _Float16* __restrict__ vTs,
                                                 const int* __restrict__ mask,
                                                 _Float16* __restrict__ attn_out) {
    const int s0   = blockIdx.x * 16;
    const int g    = blockIdx.y;
    const int tid  = threadIdx.x;
    const int lane = tid & 63;
    const int wv   = tid >> 6;
    const int h    = g * 4 + wv;
    const int lr   = lane & 15;
    const int quad = lane >> 4;

    __shared__ __align__(16) _Float16 K_lds[80 * 72];
    __shared__ __align__(16) _Float16 Vt_lds[64 * 104];
    __shared__ __align__(16) _Float16 P_lds[4][16 * 104];
    __shared__ int M_lds[1024];

    ((int4*)M_lds)[tid] = ((const int4*)(mask + s0 * 64))[tid];

    // K band: rows 0..79, key j = s0-64+r (zero j<0; r=0 is masked later anyway)
    for (int c = tid; c < 640; c += 256) {
        int r = c >> 3, cl = c & 7;
        int j = s0 - 64 + r;
        f16x8 val = {};
        if (j >= 0)
            val = *(const f16x8*)(qkv + (size_t)j * NQKV + 1024 + g * 64 + cl * 8);
        *(f16x8*)&K_lds[r * 72 + cl * 8] = val;
    }
    // V band from pre-transposed vTs: Vt_lds[d][r] = vTs[g*64+d][s0 + r], r 0..95.
    // Front halo of vTs is zero; tail reads are finite garbage multiplied by P=0.
    for (int c = tid; c < 64 * 12; c += 256) {
        int d = c / 12, ch = c % 12;
        *(f16x8*)&Vt_lds[d * 104 + ch * 8] =
            *(const f16x8*)(vTs + (size_t)(g * 64 + d) * VW + s0 + ch * 8);
    }

    // Q frags (already roped + 0.125-scaled)
    f16x8 qf[2];
#pragma unroll
    for (int ks = 0; ks < 2; ++ks)
        qf[ks] = *(const f16x8*)(qkv + (size_t)(s0 + lr) * NQKV + h * 64 + ks * 32 + quad * 8);
    __syncthreads();

    // QK^T: 5 key tiles x 2 k-steps
    f32x4 sc[5];
#pragma unroll
    for (int t = 0; t < 5; ++t) {
        f32x4 a = {};
#pragma unroll
        for (int ks = 0; ks < 2; ++ks) {
            f16x8 kf = *(const f16x8*)&K_lds[(t * 16 + lr) * 72 + ks * 32 + quad * 8];
            a = __builtin_amdgcn_mfma_f32_16x16x32_f16(qf[ks], kf, a, 0, 0, 0);
        }
        sc[t] = a;
    }

    // window + attention_mask: w = r - 1 - qi must be in [0,64)
#pragma unroll
    for (int t = 0; t < 5; ++t)
#pragma unroll
        for (int r = 0; r < 4; ++r) {
            int qi = quad * 4 + r;
            int w  = t * 16 + lr - 1 - qi;
            bool ok = (w >= 0) && (w < 64) && (M_lds[qi * 64 + (w & 63)] > 0);
            sc[t][r] = ok ? sc[t][r] : -1e30f;
        }

    // softmax across the 16 lanes of each quad-row
    float pr[5][4];
#pragma unroll
    for (int r = 0; r < 4; ++r) {
        float mx = -1e30f;
#pragma unroll
        for (int t = 0; t < 5; ++t) mx = fmaxf(mx, sc[t][r]);
#pragma unroll
        for (int off = 1; off < 16; off <<= 1) mx = fmaxf(mx, __shfl_xor(mx, off));
        float sum = 0.f;
#pragma unroll
        for (int t = 0; t < 5; ++t) { float e = __expf(sc[t][r] - mx); pr[t][r] = e; sum += e; }
#pragma unroll
        for (int off = 1; off < 16; off <<= 1) sum += __shfl_xor(sum, off);
        float rs = 1.0f / sum;
#pragma unroll
        for (int t = 0; t < 5; ++t) pr[t][r] *= rs;
    }

    // P -> LDS in A-frag layout; zero pad cols 80..95
    _Float16* myP = P_lds[wv];
    {
        f16x4 z = {};
        *(f16x4*)&myP[lr * 104 + 80 + quad * 4] = z;
    }
#pragma unroll
    for (int t = 0; t < 5; ++t)
#pragma unroll
        for (int r = 0; r < 4; ++r)
            myP[(quad * 4 + r) * 104 + t * 16 + lr] = (_Float16)pr[t][r];
    __syncthreads();

    // PV
    f32x4 oacc[4] = {};
#pragma unroll
    for (int ks = 0; ks < 3; ++ks) {
        f16x8 pf = *(const f16x8*)&myP[lr * 104 + ks * 32 + quad * 8];
#pragma unroll
        for (int t = 0; t < 4; ++t) {
            f16x8 vf = *(const f16x8*)&Vt_lds[(t * 16 + lr) * 104 + ks * 32 + quad * 8];
            oacc[t] = __builtin_amdgcn_mfma_f32_16x16x32_f16(pf, vf, oacc[t], 0, 0, 0);
        }
    }
#pragma unroll
    for (int t = 0; t < 4; ++t)
#pragma unroll
        for (int r = 0; r < 4; ++r)
            attn_out[(size_t)(s0 + quad * 4 + r) * HIDDEN + h * 64 + t * 16 + lr] = (_Float16)oacc[t][r];
}

// ---------------- launch ----------------
extern "C" void kernel_launch(void* const* d_in, const int* in_sizes, int n_in,
                              void* d_out, int out_size, void* d_ws, size_t ws_size,
                              hipStream_t stream) {
    const float* hs      = (const float*)d_in[0];
    const int*   mask    = (const int*)  d_in[1];
    const int*   pos_ids = (const int*)  d_in[2];
    const float* wq      = (const float*)d_in[3];
    const float* wk      = (const float*)d_in[4];
    const float* wvv     = (const float*)d_in[5];
    const float* wo      = (const float*)d_in[6];
    float* out = (float*)d_out;

    char* ws = (char*)d_ws;
    _Float16* wqkvT   = (_Float16*)(ws + 0);                    // 1536x1024 f16 (3 MB)
    _Float16* woT     = (_Float16*)(ws + (3u << 20));           // 1024x1024 f16 (2 MB)
    _Float16* hsf16   = (_Float16*)(ws + (5u << 20));           // 2048x1024 f16 (4 MB)
    _Float16* qkvf16  = (_Float16*)(ws + (9u << 20));           // 2048x1536 f16 (6 MB)
    _Float16* attnf16 = (_Float16*)(ws + (15u << 20));          // 2048x1024 f16 (4 MB)
    _Float16* vTs     = (_Float16*)(ws + (19u << 20));          // 256x2128  f16 (~1.1 MB)
    float2*   ropeTab = (float2*)  (ws + (21u << 20));          // 2048x32 float2 (512 KB)

    // 1. prep: transposes (2560) + convert (2048) + rope table (256) + v halo (256)
    prep_kernel<<<5120, 256, 0, stream>>>(hs, hsf16, wq, wk, wvv, wo, wqkvT, woT,
                                          pos_ids, ropeTab, vTs);
    // 2. QKV projection with fused rope / v-transpose
    gemm_qkv<<<dim3(NQKV / 64, S / 128), 256, 0, stream>>>(hsf16, wqkvT, qkvf16, vTs, ropeTab);
    // 3. attention
    attn_mfma<<<dim3(S / 16, NKV), 256, 0, stream>>>(qkvf16, vTs, mask, attnf16);
    // 4. output projection -> f32 out
    gemm_o<<<dim3(HIDDEN / 64, S / 128), 256, 0, stream>>>(attnf16, woT, out);
}